// Round 2
// 353.369 us; speedup vs baseline: 1.2775x; 1.2775x over previous
//
#include <hip/hip_runtime.h>
#include <hip/hip_fp16.h>

#define N_NODES 50000
#define N_EDGES 800000
#define D_FEAT 64
#define K_HOPS 8
#define OUT_STRIDE ((K_HOPS + 1) * D_FEAT)  // 576
#define NXCD 8

// ---------------- ws layout (bytes) ----------------
// degs+hists contiguous (one memset). XA (fp16 ping buffer, (N+1) rows: row N
// is the hot zero-row for predicated gathers) overlays degs/hists/aux (dead
// after scatter; XA first written by hop 1, which runs after scatter).
#define ALIGN256(x) (((x) + 255) & ~(size_t)255)
static const size_t OFF_DEGS  = 0;                                          // int[8][N]
static const size_t OFF_HISTS = OFF_DEGS + (size_t)NXCD * N_NODES * 4;      // int[8][N]
static const size_t OFF_AUX   = ALIGN256(OFF_HISTS + (size_t)NXCD * N_NODES * 4); // int[E]
static const size_t XA_BYTES  = (size_t)(N_NODES + 1) * D_FEAT * 2;         // 6,400,128
static const size_t AUX_END   = OFF_AUX + (size_t)N_EDGES * 4;              // 6,400,000
static const size_t OFF_XA    = 0;                                          // overlay
static const size_t OFF_DINV  = ALIGN256(AUX_END > XA_BYTES ? AUX_END : XA_BYTES);
static const size_t OFF_OFF   = ALIGN256(OFF_DINV  + (size_t)N_NODES * 4);  // int[N+1]
static const size_t OFF_BSUM  = ALIGN256(OFF_OFF   + (size_t)(N_NODES + 1) * 4); // int[64]
static const size_t OFF_BASES = ALIGN256(OFF_BSUM  + 64 * 4);               // int[8][N]
static const size_t OFF_CSR   = ALIGN256(OFF_BASES + (size_t)NXCD * N_NODES * 4); // int[E]
static const size_t OFF_XB    = ALIGN256(OFF_CSR   + (size_t)N_EDGES * 4);  // half[(N+1)*64]

#define SCAN_BLOCK_ELEMS 1024
#define SCAN_NB ((N_NODES + SCAN_BLOCK_ELEMS - 1) / SCAN_BLOCK_ELEMS)  // 49

// HW_REG_XCC_ID = 20 (gfx940+); simm16 = (size-1)<<11 | offset<<6 | id
__device__ __forceinline__ unsigned xcc_id() {
    return __builtin_amdgcn_s_getreg((31u << 11) | 20u) & (NXCD - 1);
}

__device__ __forceinline__ unsigned pack_h2(float a, float b) {
    union { __half2 h; unsigned u; } c;
    c.h = __floats2half2_rn(a, b);
    return c.u;
}
__device__ __forceinline__ float2 unpack_h2(unsigned u) {
    union { unsigned u; __half2 h; } c;
    c.u = u;
    return __half22float2(c.h);
}

// ---------------- preprocessing kernels ----------------

// Per-XCD private histograms; aux[e] records (xcd, slot-within-subbucket)
// so the scatter needs NO atomics.
__global__ void k_count(const int* __restrict__ src, const int* __restrict__ dst,
                        int* __restrict__ degs, int* __restrict__ hists,
                        int* __restrict__ aux) {
    int e = blockIdx.x * blockDim.x + threadIdx.x;
    if (e >= N_EDGES) return;
    int s = src[e], d = dst[e];
    if (s == d) { aux[e] = -1; return; }
    unsigned x = xcc_id();
    __hip_atomic_fetch_add(&degs[x * N_NODES + s], 1,
                           __ATOMIC_RELAXED, __HIP_MEMORY_SCOPE_WORKGROUP);
    int pw = __hip_atomic_fetch_add(&hists[x * N_NODES + d], 1,
                                    __ATOMIC_RELAXED, __HIP_MEMORY_SCOPE_WORKGROUP);
    aux[e] = (int)((x << 28) | (unsigned)pw);
}

__global__ void k_deg(const int* __restrict__ degs, float* __restrict__ dinv) {
    int i = blockIdx.x * blockDim.x + threadIdx.x;
    if (i >= N_NODES) return;
    int s = 1;  // self loop
    #pragma unroll
    for (int c = 0; c < NXCD; ++c) s += degs[c * N_NODES + i];
    dinv[i] = rsqrtf((float)s);
}

// scan stage 1: per-block sums of 1024-elem chunks (summed over 8 copies)
__global__ void k_scan_sums(const int* __restrict__ hists, int* __restrict__ bsum) {
    __shared__ int lds[256];
    int b = blockIdx.x, t = threadIdx.x;
    int base = b * SCAN_BLOCK_ELEMS;
    int s = 0;
    for (int j = t; j < SCAN_BLOCK_ELEMS; j += 256) {
        int idx = base + j;
        if (idx < N_NODES) {
            #pragma unroll
            for (int c = 0; c < NXCD; ++c) s += hists[c * N_NODES + idx];
        }
    }
    lds[t] = s; __syncthreads();
    for (int str = 128; str > 0; str >>= 1) {
        if (t < str) lds[t] += lds[t + str];
        __syncthreads();
    }
    if (t == 0) bsum[b] = lds[0];
}

// scan stage 2: single-wave exclusive scan of the 49 block sums
__global__ void k_scan_top(int* __restrict__ bsum) {
    int lane = threadIdx.x;  // blockDim = 64
    int orig = (lane < SCAN_NB) ? bsum[lane] : 0;
    int v = orig;
    for (int d = 1; d < 64; d <<= 1) {
        int u = __shfl_up(v, d, 64);
        if (lane >= d) v += u;
    }
    if (lane < SCAN_NB) bsum[lane] = v - orig;  // exclusive
}

// scan stage 3: down-sweep; writes off[] and per-(xcd,node) base offsets
__global__ void k_scan_down(const int* __restrict__ hists, const int* __restrict__ bsum,
                            int* __restrict__ off, int* __restrict__ bases) {
    __shared__ int lds[256];
    int b = blockIdx.x, t = threadIdx.x;
    int base = b * SCAN_BLOCK_ELEMS + t * 4;
    int tot[4];
    #pragma unroll
    for (int j = 0; j < 4; ++j) {
        int idx = base + j; int s = 0;
        if (idx < N_NODES) {
            #pragma unroll
            for (int c = 0; c < NXCD; ++c) s += hists[c * N_NODES + idx];
        }
        tot[j] = s;
    }
    int tsum = tot[0] + tot[1] + tot[2] + tot[3];
    lds[t] = tsum; __syncthreads();
    int x = tsum;
    for (int d = 1; d < 256; d <<= 1) {   // Hillis-Steele inclusive scan
        int u = (t >= d) ? lds[t - d] : 0;
        __syncthreads();
        x += u;
        lds[t] = x;
        __syncthreads();
    }
    int p = (x - tsum) + bsum[b];
    #pragma unroll
    for (int j = 0; j < 4; ++j) {
        int idx = base + j;
        if (idx < N_NODES) {
            off[idx] = p;
            #pragma unroll
            for (int c = 0; c < NXCD; ++c) {
                bases[c * N_NODES + idx] = p;
                p += hists[c * N_NODES + idx];
            }
        } else if (idx == N_NODES) {
            off[idx] = p;
        }
    }
}

// atomic-free scatter: slot = bases[xcd][d] + pos_within (from aux).
// Weight-free CSR: entry is just the source node id (no dinv gathers here).
__global__ void k_scatter(const int* __restrict__ src, const int* __restrict__ dst,
                          const int* __restrict__ aux, const int* __restrict__ bases,
                          int* __restrict__ csr) {
    int e = blockIdx.x * blockDim.x + threadIdx.x;
    if (e >= N_EDGES) return;
    int a = aux[e];
    if (a < 0) return;  // self loop
    int s = src[e], d = dst[e];
    unsigned x = (unsigned)a >> 28;
    int pw = a & 0x0FFFFFFF;
    int pos = bases[x * N_NODES + d] + pw;
    csr[pos] = s;
}

// ---------------- compute kernels ----------------

// x0: feature -> out col 0 (fp32) and XB = y0 = dinv * x (fp16 compact).
// Also zeroes row N of XB (the predication zero-row for hop gathers).
__global__ void k_x0(const float4* __restrict__ feat4, float4* __restrict__ out4,
                     uint2* __restrict__ y0, const float* __restrict__ dinv) {
    int t = blockIdx.x * blockDim.x + threadIdx.x;  // over (N+1)*16
    if (t >= (N_NODES + 1) * 16) return;
    int row = t >> 4;
    if (row < N_NODES) {
        float4 v = feat4[t];
        out4[(size_t)row * (OUT_STRIDE / 4) + (t & 15)] = v;
        float di = dinv[row];
        uint2 w;
        w.x = pack_h2(v.x * di, v.y * di);
        w.y = pack_h2(v.z * di, v.w * di);
        y0[t] = w;
    } else {
        y0[t] = make_uint2(0u, 0u);  // zero row
    }
}

// Quad-node hop: 4 nodes per wave (16 lanes x 8B each -> one gather
// instruction fetches 4 rows of 128B). Weight-free accumulate:
//   t_i = sum_{j->i} y[j] + y[i];  out_k[i] = dinv_i * t_i;  y_k[i] = dinv_i^2 * t_i.
// Loop bound = max degree over the 4 nodes; exhausted lanes gather the
// L1-hot zero row (index N_NODES). csr indices prefetched one chunk ahead.
template <bool WRITE_HALF>
__global__ __launch_bounds__(256) void k_hop4(
    const uint2* __restrict__ yin,   // (N+1) x 16 x uint2
    float4* __restrict__ outcol4,    // (float4*)out + k*16; row stride 144
    uint2* __restrict__ yout,
    const int* __restrict__ off, const int* __restrict__ csr,
    const float* __restrict__ dinv) {
    int qw = (blockIdx.x * blockDim.x + threadIdx.x) >> 6;  // quad id, < 12500
    int lane = threadIdx.x & 63;
    int f = lane & 15;                 // feature quad: features [4f, 4f+4)
    int node = qw * 4 + (lane >> 4);   // < 50000 exactly
    int e0 = off[node], e1 = off[node + 1];
    float di = dinv[node];
    uint2 sv = yin[node * 16 + f];
    float2 lo = unpack_h2(sv.x), hi = unpack_h2(sv.y);
    float a0 = lo.x, a1 = lo.y, a2 = hi.x, a3 = hi.y;  // self term (weight dinv^2)

    int nm = e1 - e0;  // wave-wide max degree
    #pragma unroll
    for (int d = 32; d; d >>= 1) nm = max(nm, __shfl_xor(nm, d, 64));

    auto FETCH = [&](int j) -> int {
        int idx = e0 + j;
        int c = csr[idx < e1 ? idx : 0];  // safe broadcast addr
        return (idx < e1) ? c : N_NODES;  // zero row when exhausted
    };

    int c0 = FETCH(0), c1 = FETCH(1), c2 = FETCH(2), c3 = FETCH(3);
    for (int j = 0; j < nm; j += 4) {
        int d0 = FETCH(j + 4), d1 = FETCH(j + 5), d2 = FETCH(j + 6), d3 = FETCH(j + 7);
        uint2 q0 = yin[c0 * 16 + f];
        uint2 q1 = yin[c1 * 16 + f];
        uint2 q2 = yin[c2 * 16 + f];
        uint2 q3 = yin[c3 * 16 + f];
        float2 t;
        t = unpack_h2(q0.x); a0 += t.x; a1 += t.y;
        t = unpack_h2(q0.y); a2 += t.x; a3 += t.y;
        t = unpack_h2(q1.x); a0 += t.x; a1 += t.y;
        t = unpack_h2(q1.y); a2 += t.x; a3 += t.y;
        t = unpack_h2(q2.x); a0 += t.x; a1 += t.y;
        t = unpack_h2(q2.y); a2 += t.x; a3 += t.y;
        t = unpack_h2(q3.x); a0 += t.x; a1 += t.y;
        t = unpack_h2(q3.y); a2 += t.x; a3 += t.y;
        c0 = d0; c1 = d1; c2 = d2; c3 = d3;
    }

    outcol4[(size_t)node * (OUT_STRIDE / 4) + f] =
        make_float4(di * a0, di * a1, di * a2, di * a3);
    if (WRITE_HALF) {
        float di2 = di * di;
        uint2 w;
        w.x = pack_h2(di2 * a0, di2 * a1);
        w.y = pack_h2(di2 * a2, di2 * a3);
        yout[node * 16 + f] = w;
        if (blockIdx.x == 0 && threadIdx.x < 16)
            yout[N_NODES * 16 + threadIdx.x] = make_uint2(0u, 0u);  // zero row
    }
}

// ---------------- launch ----------------

extern "C" void kernel_launch(void* const* d_in, const int* in_sizes, int n_in,
                              void* d_out, int out_size, void* d_ws, size_t ws_size,
                              hipStream_t stream) {
    const float* feature = (const float*)d_in[0];
    const int* edge = (const int*)d_in[1];
    const int* src = edge;            // edge_index[0]
    const int* dst = edge + N_EDGES;  // edge_index[1]
    float* out = (float*)d_out;
    char* ws = (char*)d_ws;

    int*    degs  = (int*)(ws + OFF_DEGS);
    int*    hists = (int*)(ws + OFF_HISTS);
    int*    aux   = (int*)(ws + OFF_AUX);
    float*  dinv  = (float*)(ws + OFF_DINV);
    int*    off   = (int*)(ws + OFF_OFF);
    int*    bsum  = (int*)(ws + OFF_BSUM);
    int*    bases = (int*)(ws + OFF_BASES);
    int*    csr   = (int*)(ws + OFF_CSR);
    uint2*  xa    = (uint2*)(ws + OFF_XA);  // overlays degs/hists/aux (dead by hop 1)
    uint2*  xb    = (uint2*)(ws + OFF_XB);

    const int TB = 256;
    // ---- build normalization + CSR (re-run every call: ws is re-poisoned)
    hipMemsetAsync(ws + OFF_DEGS, 0, (size_t)2 * NXCD * N_NODES * 4, stream);
    k_count<<<(N_EDGES + TB - 1) / TB, TB, 0, stream>>>(src, dst, degs, hists, aux);
    k_deg<<<(N_NODES + TB - 1) / TB, TB, 0, stream>>>(degs, dinv);
    k_x0<<<((N_NODES + 1) * 16 + TB - 1) / TB, TB, 0, stream>>>(
        (const float4*)feature, (float4*)out, xb, dinv);
    k_scan_sums<<<SCAN_NB, 256, 0, stream>>>(hists, bsum);
    k_scan_top<<<1, 64, 0, stream>>>(bsum);
    k_scan_down<<<SCAN_NB, 256, 0, stream>>>(hists, bsum, off, bases);
    k_scatter<<<(N_EDGES + TB - 1) / TB, TB, 0, stream>>>(src, dst, aux, bases, csr);
    // ---- K hops, fp16 ping-pong y buffers (XB -> XA -> XB -> ...)
    const int hop_blocks = (N_NODES / 4) * 64 / TB;  // 3125
    for (int k = 1; k <= K_HOPS; ++k) {
        const uint2* yin = (k & 1) ? xb : xa;
        uint2* yout      = (k & 1) ? xa : xb;
        float4* outcol4 = (float4*)out + (size_t)k * 16;
        if (k < K_HOPS)
            k_hop4<true><<<hop_blocks, TB, 0, stream>>>(yin, outcol4, yout, off, csr, dinv);
        else
            k_hop4<false><<<hop_blocks, TB, 0, stream>>>(yin, outcol4, nullptr, off, csr, dinv);
    }
}

// Round 3
// 344.070 us; speedup vs baseline: 1.3120x; 1.0270x over previous
//
#include <hip/hip_runtime.h>
#include <hip/hip_fp16.h>

#define N_NODES 50000
#define N_EDGES 800000
#define D_FEAT 64
#define K_HOPS 8
#define OUT_STRIDE ((K_HOPS + 1) * D_FEAT)  // 576
#define NXCD 8
#define NPART 64            // LDS src-degree partial copies
#define PART_CHUNK (N_EDGES / NPART)  // 12500
#define NWORD (N_NODES / 2) // packed 2-nodes-per-u32 histogram words

// ---------------- ws layout (bytes) ----------------
// hists+aux at the front; XA (fp16 ping buffer, rows [0,N]; row N = zero row)
// overlays them (dead after scatter; XA first written by hop 1).
// part (src-deg partials, 6.4 MB) overlays the XB region: part is dead after
// k_deg, and XB is first written by k_x0 which runs after k_deg.
#define ALIGN256(x) (((x) + 255) & ~(size_t)255)
static const size_t OFF_HISTS = 0;                                          // int[8][N]
static const size_t OFF_AUX   = ALIGN256(OFF_HISTS + (size_t)NXCD * N_NODES * 4); // int[E]
static const size_t AUX_END   = OFF_AUX + (size_t)N_EDGES * 4;              // 4,800,000
static const size_t XA_BYTES  = (size_t)(N_NODES + 1) * D_FEAT * 2;         // 6,400,128
static const size_t OFF_XA    = 0;                                          // overlay
static const size_t OFF_DINV  = ALIGN256(AUX_END > XA_BYTES ? AUX_END : XA_BYTES);
static const size_t OFF_OFF   = ALIGN256(OFF_DINV  + (size_t)N_NODES * 4);  // int[N+1]
static const size_t OFF_BSUM  = ALIGN256(OFF_OFF   + (size_t)(N_NODES + 1) * 4); // int[64]
static const size_t OFF_BASES = ALIGN256(OFF_BSUM  + 64 * 4);               // int[8][N]
static const size_t OFF_CSR   = ALIGN256(OFF_BASES + (size_t)NXCD * N_NODES * 4); // int[E]
static const size_t OFF_XB    = ALIGN256(OFF_CSR   + (size_t)N_EDGES * 4);  // half[(N+1)*64]
static const size_t OFF_PART  = OFF_XB;  // u32[64][25000] = 6,400,000 <= XB bytes (overlay)

#define SCAN_BLOCK_ELEMS 1024
#define SCAN_NB ((N_NODES + SCAN_BLOCK_ELEMS - 1) / SCAN_BLOCK_ELEMS)  // 49

// HW_REG_XCC_ID = 20 (gfx940+); simm16 = (size-1)<<11 | offset<<6 | id
__device__ __forceinline__ unsigned xcc_id() {
    return __builtin_amdgcn_s_getreg((31u << 11) | 20u) & (NXCD - 1);
}

__device__ __forceinline__ unsigned pack_h2(float a, float b) {
    union { __half2 h; unsigned u; } c;
    c.h = __floats2half2_rn(a, b);
    return c.u;
}
__device__ __forceinline__ float2 unpack_h2(unsigned u) {
    union { unsigned u; __half2 h; } c;
    c.u = u;
    return __half22float2(c.h);
}

// ---------------- preprocessing kernels ----------------

// dst histogram ONLY (global atomics; 800K ops). aux[e] = (xcd, slot) so the
// scatter needs no atomics. (rocprof r2: each global atomic costs a 32B
// memory-side RMW -> ~21 Gops/s; so the src-deg histogram moved to LDS.)
__global__ void k_count(const int* __restrict__ src, const int* __restrict__ dst,
                        int* __restrict__ hists, int* __restrict__ aux) {
    int e = blockIdx.x * blockDim.x + threadIdx.x;
    if (e >= N_EDGES) return;
    int s = src[e], d = dst[e];
    if (s == d) { aux[e] = -1; return; }
    unsigned x = xcc_id();
    int pw = __hip_atomic_fetch_add(&hists[x * N_NODES + d], 1,
                                    __ATOMIC_RELAXED, __HIP_MEMORY_SCOPE_WORKGROUP);
    aux[e] = (int)((x << 28) | (unsigned)pw);
}

// src-degree histogram in LDS: full 50K-node histogram per block as packed
// 2xu16 in 100 KB LDS; 64 blocks x 12500 edges; dump partials to global.
__global__ __launch_bounds__(256, 1) void k_srcdeg(const int* __restrict__ src,
                                                   const int* __restrict__ dst,
                                                   unsigned* __restrict__ part) {
    __shared__ unsigned h[NWORD];  // 100,000 B
    int t = threadIdx.x;
    for (int w = t; w < NWORD; w += 256) h[w] = 0u;
    __syncthreads();
    int base = blockIdx.x * PART_CHUNK;
    for (int j = t; j < PART_CHUNK; j += 256) {
        int e = base + j;
        int s = src[e], d = dst[e];
        if (s != d) atomicAdd(&h[s >> 1], (s & 1) ? 65536u : 1u);
    }
    __syncthreads();
    unsigned* out = part + (size_t)blockIdx.x * NWORD;
    for (int w = t; w < NWORD; w += 256) out[w] = h[w];
}

// reduce the 64 packed partials -> dinv (2 nodes per thread)
__global__ void k_deg(const unsigned* __restrict__ part, float* __restrict__ dinv) {
    int w = blockIdx.x * blockDim.x + threadIdx.x;
    if (w >= NWORD) return;
    unsigned s0 = 0, s1 = 0, s2 = 0, s3 = 0;
    #pragma unroll 4
    for (int b = 0; b < NPART; b += 4) {
        s0 += part[(size_t)(b + 0) * NWORD + w];
        s1 += part[(size_t)(b + 1) * NWORD + w];
        s2 += part[(size_t)(b + 2) * NWORD + w];
        s3 += part[(size_t)(b + 3) * NWORD + w];
    }
    unsigned s = (s0 + s1) + (s2 + s3);  // low sums < 2^16: no carry into high
    dinv[2 * w + 0] = rsqrtf((float)((s & 0xffffu) + 1u));
    dinv[2 * w + 1] = rsqrtf((float)((s >> 16) + 1u));
}

// scan stage 1: per-block sums of 1024-elem chunks (summed over 8 copies)
__global__ void k_scan_sums(const int* __restrict__ hists, int* __restrict__ bsum) {
    __shared__ int lds[256];
    int b = blockIdx.x, t = threadIdx.x;
    int base = b * SCAN_BLOCK_ELEMS;
    int s = 0;
    for (int j = t; j < SCAN_BLOCK_ELEMS; j += 256) {
        int idx = base + j;
        if (idx < N_NODES) {
            #pragma unroll
            for (int c = 0; c < NXCD; ++c) s += hists[c * N_NODES + idx];
        }
    }
    lds[t] = s; __syncthreads();
    for (int str = 128; str > 0; str >>= 1) {
        if (t < str) lds[t] += lds[t + str];
        __syncthreads();
    }
    if (t == 0) bsum[b] = lds[0];
}

// scan stage 2: single-wave exclusive scan of the 49 block sums
__global__ void k_scan_top(int* __restrict__ bsum) {
    int lane = threadIdx.x;  // blockDim = 64
    int orig = (lane < SCAN_NB) ? bsum[lane] : 0;
    int v = orig;
    for (int d = 1; d < 64; d <<= 1) {
        int u = __shfl_up(v, d, 64);
        if (lane >= d) v += u;
    }
    if (lane < SCAN_NB) bsum[lane] = v - orig;  // exclusive
}

// scan stage 3: down-sweep; writes off[] and per-(xcd,node) base offsets
__global__ void k_scan_down(const int* __restrict__ hists, const int* __restrict__ bsum,
                            int* __restrict__ off, int* __restrict__ bases) {
    __shared__ int lds[256];
    int b = blockIdx.x, t = threadIdx.x;
    int base = b * SCAN_BLOCK_ELEMS + t * 4;
    int tot[4];
    #pragma unroll
    for (int j = 0; j < 4; ++j) {
        int idx = base + j; int s = 0;
        if (idx < N_NODES) {
            #pragma unroll
            for (int c = 0; c < NXCD; ++c) s += hists[c * N_NODES + idx];
        }
        tot[j] = s;
    }
    int tsum = tot[0] + tot[1] + tot[2] + tot[3];
    lds[t] = tsum; __syncthreads();
    int x = tsum;
    for (int d = 1; d < 256; d <<= 1) {   // Hillis-Steele inclusive scan
        int u = (t >= d) ? lds[t - d] : 0;
        __syncthreads();
        x += u;
        lds[t] = x;
        __syncthreads();
    }
    int p = (x - tsum) + bsum[b];
    #pragma unroll
    for (int j = 0; j < 4; ++j) {
        int idx = base + j;
        if (idx < N_NODES) {
            off[idx] = p;
            #pragma unroll
            for (int c = 0; c < NXCD; ++c) {
                bases[c * N_NODES + idx] = p;
                p += hists[c * N_NODES + idx];
            }
        } else if (idx == N_NODES) {
            off[idx] = p;
        }
    }
}

// atomic-free scatter: slot = bases[xcd][d] + pos_within (from aux).
// Weight-free CSR: entry is just the source node id.
__global__ void k_scatter(const int* __restrict__ src, const int* __restrict__ dst,
                          const int* __restrict__ aux, const int* __restrict__ bases,
                          int* __restrict__ csr) {
    int e = blockIdx.x * blockDim.x + threadIdx.x;
    if (e >= N_EDGES) return;
    int a = aux[e];
    if (a < 0) return;  // self loop
    int s = src[e], d = dst[e];
    unsigned x = (unsigned)a >> 28;
    int pw = a & 0x0FFFFFFF;
    int pos = bases[x * N_NODES + d] + pw;
    csr[pos] = s;
}

// ---------------- compute kernels ----------------

// x0: feature -> out col 0 (fp32) and XB = y0 = dinv * x (fp16 compact).
// Also zeroes row N of XB (the predication zero-row for hop gathers).
__global__ void k_x0(const float4* __restrict__ feat4, float4* __restrict__ out4,
                     uint2* __restrict__ y0, const float* __restrict__ dinv) {
    int t = blockIdx.x * blockDim.x + threadIdx.x;  // over (N+1)*16
    if (t >= (N_NODES + 1) * 16) return;
    int row = t >> 4;
    if (row < N_NODES) {
        float4 v = feat4[t];
        out4[(size_t)row * (OUT_STRIDE / 4) + (t & 15)] = v;
        float di = dinv[row];
        uint2 w;
        w.x = pack_h2(v.x * di, v.y * di);
        w.y = pack_h2(v.z * di, v.w * di);
        y0[t] = w;
    } else {
        y0[t] = make_uint2(0u, 0u);  // zero row
    }
}

// Quad-node hop: 4 nodes per wave (16 lanes x 8B each -> one gather
// instruction fetches 4 rows of 128B). Weight-free accumulate:
//   t_i = sum_{j->i} y[j] + y[i];  out_k[i] = dinv_i * t_i;  y_k[i] = dinv_i^2 * t_i.
// 8-deep gather unroll with 8-wide csr prefetch: 8 outstanding VMEM loads
// per wave for latency hiding. Exhausted lanes gather the L1-hot zero row.
template <bool WRITE_HALF>
__global__ __launch_bounds__(256) void k_hop4(
    const uint2* __restrict__ yin,   // (N+1) x 16 x uint2
    float4* __restrict__ outcol4,    // (float4*)out + k*16; row stride 144
    uint2* __restrict__ yout,
    const int* __restrict__ off, const int* __restrict__ csr,
    const float* __restrict__ dinv) {
    int qw = (blockIdx.x * blockDim.x + threadIdx.x) >> 6;  // quad id, < 12500
    int lane = threadIdx.x & 63;
    int f = lane & 15;                 // feature quad: features [4f, 4f+4)
    int node = qw * 4 + (lane >> 4);   // < 50000 exactly
    int e0 = off[node], e1 = off[node + 1];
    float di = dinv[node];
    uint2 sv = yin[node * 16 + f];
    float2 lo = unpack_h2(sv.x), hi = unpack_h2(sv.y);
    float a0 = lo.x, a1 = lo.y, a2 = hi.x, a3 = hi.y;  // self term

    int nm = e1 - e0;  // wave-wide max degree
    #pragma unroll
    for (int d = 32; d; d >>= 1) nm = max(nm, __shfl_xor(nm, d, 64));

    auto FETCH = [&](int j) -> int {
        int idx = e0 + j;
        int c = csr[idx < e1 ? idx : 0];  // safe broadcast addr
        return (idx < e1) ? c : N_NODES;  // zero row when exhausted
    };

    int c0 = FETCH(0), c1 = FETCH(1), c2 = FETCH(2), c3 = FETCH(3);
    int c4 = FETCH(4), c5 = FETCH(5), c6 = FETCH(6), c7 = FETCH(7);
    for (int j = 0; j < nm; j += 8) {
        int d0 = FETCH(j + 8),  d1 = FETCH(j + 9),  d2 = FETCH(j + 10), d3 = FETCH(j + 11);
        int d4 = FETCH(j + 12), d5 = FETCH(j + 13), d6 = FETCH(j + 14), d7 = FETCH(j + 15);
        uint2 q0 = yin[c0 * 16 + f];
        uint2 q1 = yin[c1 * 16 + f];
        uint2 q2 = yin[c2 * 16 + f];
        uint2 q3 = yin[c3 * 16 + f];
        uint2 q4 = yin[c4 * 16 + f];
        uint2 q5 = yin[c5 * 16 + f];
        uint2 q6 = yin[c6 * 16 + f];
        uint2 q7 = yin[c7 * 16 + f];
        float2 t;
        t = unpack_h2(q0.x); a0 += t.x; a1 += t.y;
        t = unpack_h2(q0.y); a2 += t.x; a3 += t.y;
        t = unpack_h2(q1.x); a0 += t.x; a1 += t.y;
        t = unpack_h2(q1.y); a2 += t.x; a3 += t.y;
        t = unpack_h2(q2.x); a0 += t.x; a1 += t.y;
        t = unpack_h2(q2.y); a2 += t.x; a3 += t.y;
        t = unpack_h2(q3.x); a0 += t.x; a1 += t.y;
        t = unpack_h2(q3.y); a2 += t.x; a3 += t.y;
        t = unpack_h2(q4.x); a0 += t.x; a1 += t.y;
        t = unpack_h2(q4.y); a2 += t.x; a3 += t.y;
        t = unpack_h2(q5.x); a0 += t.x; a1 += t.y;
        t = unpack_h2(q5.y); a2 += t.x; a3 += t.y;
        t = unpack_h2(q6.x); a0 += t.x; a1 += t.y;
        t = unpack_h2(q6.y); a2 += t.x; a3 += t.y;
        t = unpack_h2(q7.x); a0 += t.x; a1 += t.y;
        t = unpack_h2(q7.y); a2 += t.x; a3 += t.y;
        c0 = d0; c1 = d1; c2 = d2; c3 = d3;
        c4 = d4; c5 = d5; c6 = d6; c7 = d7;
    }

    outcol4[(size_t)node * (OUT_STRIDE / 4) + f] =
        make_float4(di * a0, di * a1, di * a2, di * a3);
    if (WRITE_HALF) {
        float di2 = di * di;
        uint2 w;
        w.x = pack_h2(di2 * a0, di2 * a1);
        w.y = pack_h2(di2 * a2, di2 * a3);
        yout[node * 16 + f] = w;
        if (blockIdx.x == 0 && threadIdx.x < 16)
            yout[N_NODES * 16 + threadIdx.x] = make_uint2(0u, 0u);  // zero row
    }
}

// ---------------- launch ----------------

extern "C" void kernel_launch(void* const* d_in, const int* in_sizes, int n_in,
                              void* d_out, int out_size, void* d_ws, size_t ws_size,
                              hipStream_t stream) {
    const float* feature = (const float*)d_in[0];
    const int* edge = (const int*)d_in[1];
    const int* src = edge;            // edge_index[0]
    const int* dst = edge + N_EDGES;  // edge_index[1]
    float* out = (float*)d_out;
    char* ws = (char*)d_ws;

    int*      hists = (int*)(ws + OFF_HISTS);
    int*      aux   = (int*)(ws + OFF_AUX);
    unsigned* part  = (unsigned*)(ws + OFF_PART);  // overlays XB (dead by k_x0)
    float*    dinv  = (float*)(ws + OFF_DINV);
    int*      off   = (int*)(ws + OFF_OFF);
    int*      bsum  = (int*)(ws + OFF_BSUM);
    int*      bases = (int*)(ws + OFF_BASES);
    int*      csr   = (int*)(ws + OFF_CSR);
    uint2*    xa    = (uint2*)(ws + OFF_XA);  // overlays hists/aux (dead by hop 1)
    uint2*    xb    = (uint2*)(ws + OFF_XB);

    const int TB = 256;
    // ---- build normalization + CSR (re-run every call: ws is re-poisoned)
    hipMemsetAsync(ws + OFF_HISTS, 0, (size_t)NXCD * N_NODES * 4, stream);
    k_count<<<(N_EDGES + TB - 1) / TB, TB, 0, stream>>>(src, dst, hists, aux);
    k_srcdeg<<<NPART, 256, 0, stream>>>(src, dst, part);
    k_deg<<<(NWORD + TB - 1) / TB, TB, 0, stream>>>(part, dinv);
    k_x0<<<((N_NODES + 1) * 16 + TB - 1) / TB, TB, 0, stream>>>(
        (const float4*)feature, (float4*)out, xb, dinv);
    k_scan_sums<<<SCAN_NB, 256, 0, stream>>>(hists, bsum);
    k_scan_top<<<1, 64, 0, stream>>>(bsum);
    k_scan_down<<<SCAN_NB, 256, 0, stream>>>(hists, bsum, off, bases);
    k_scatter<<<(N_EDGES + TB - 1) / TB, TB, 0, stream>>>(src, dst, aux, bases, csr);
    // ---- K hops, fp16 ping-pong y buffers (XB -> XA -> XB -> ...)
    const int hop_blocks = (N_NODES / 4) * 64 / TB;  // 3125
    for (int k = 1; k <= K_HOPS; ++k) {
        const uint2* yin = (k & 1) ? xb : xa;
        uint2* yout      = (k & 1) ? xa : xb;
        float4* outcol4 = (float4*)out + (size_t)k * 16;
        if (k < K_HOPS)
            k_hop4<true><<<hop_blocks, TB, 0, stream>>>(yin, outcol4, yout, off, csr, dinv);
        else
            k_hop4<false><<<hop_blocks, TB, 0, stream>>>(yin, outcol4, nullptr, off, csr, dinv);
    }
}